// Round 2
// baseline (1046.804 us; speedup 1.0000x reference)
//
#include <hip/hip_runtime.h>
#include <cstdint>
#include <cstddef>

#define T_ 3
#define B_ 2
#define Y_ 192
#define X_ 192
#define YX_ 36864          // Y_*X_
#define N_ 221184          // T_*B_*Y_*X_
#define NS_ 73728          // B_*Y_*X_
#define NTILE_ 4608        // B_*(Y_/4)*(X_/4)

typedef __attribute__((ext_vector_type(8))) short short8;
typedef __attribute__((ext_vector_type(4))) float f32x4;
typedef __attribute__((ext_vector_type(4))) unsigned int u32x4;
typedef unsigned short u16;
typedef unsigned int u32;

__device__ __forceinline__ u16 f2bf(float f){
  u32 x = __builtin_bit_cast(u32, f);
  x += 0x7fffu + ((x >> 16) & 1u);          // RNE
  return (u16)(x >> 16);
}
__device__ __forceinline__ u16 f2bf_fast(float f){   // round-half-up (positive values)
  u32 x = __builtin_bit_cast(u32, f);
  return (u16)((x + 0x8000u) >> 16);
}
__device__ __forceinline__ float bflo(u32 u){ return __builtin_bit_cast(float, u << 16); }
__device__ __forceinline__ float bfhi(u32 u){ return __builtin_bit_cast(float, u & 0xffff0000u); }
__device__ __forceinline__ int clampi(int v, int lo, int hi){ return v < lo ? lo : (v > hi ? hi : v); }

// ---------------- kernel 0: weights -> bf16 n-major; spatial_emb -> bf16 ----------------
__global__ __launch_bounds__(256) void wt_kernel(
    const float* __restrict__ Wq, const float* __restrict__ Wk,
    const float* __restrict__ Wv, const float* __restrict__ Wo,
    const float* __restrict__ spatial_emb, u16* __restrict__ WT, u16* __restrict__ se_bf){
  int idx = blockIdx.x * 256 + threadIdx.x;
  if (idx < 65536){
    int g = idx >> 14;
    int r = (idx >> 7) & 127;                   // k
    int c = idx & 127;                          // n
    const float* W = (g == 0) ? Wq : (g == 1) ? Wk : (g == 2) ? Wv : Wo;
    WT[g * 16384 + c * 128 + r] = f2bf(W[r * 128 + c]);
  } else if (idx < 65536 + 3200){
    se_bf[idx - 65536] = f2bf(spatial_emb[idx - 65536]);
  }
}

// ---------------- kernel 1: fused QKV projection + embeddings ----------------
// One pass over frames; g=0 Q (emb + 0.25 prescale), g=1 K (temp emb), g=2 V -> transposed Vt
__global__ __launch_bounds__(256) void qkv_kernel(
    const float* __restrict__ frames, const u16* __restrict__ WT,
    u16* __restrict__ Qb, u16* __restrict__ Kb, u16* __restrict__ Vt,
    const float* __restrict__ temp_emb, const float* __restrict__ spatial_emb){
  __shared__ float tile[128 * 128];
  const int tid = threadIdx.x;
  const int w = tid >> 6, l = tid & 63;
  const int l16 = l & 15, lg = l >> 4;
  const int m0 = blockIdx.x * 128;

  for (int g = 0; g < 3; ++g){
    const u16* wt = WT + g * 16384;
    f32x4 acc[2][8];
    #pragma unroll
    for (int mr = 0; mr < 2; ++mr)
      #pragma unroll
      for (int nf = 0; nf < 8; ++nf)
        acc[mr][nf] = (f32x4){0.f, 0.f, 0.f, 0.f};

    #pragma unroll
    for (int ks = 0; ks < 4; ++ks){
      short8 af[2];
      #pragma unroll
      for (int mr = 0; mr < 2; ++mr){
        const float* ap = frames + (size_t)(m0 + w * 32 + mr * 16 + l16) * 128 + ks * 32 + lg * 8;
        const f32x4 a0 = *(const f32x4*)ap;
        const f32x4 a1 = *(const f32x4*)(ap + 4);
        short8 t;
        t[0] = (short)f2bf(a0[0]); t[1] = (short)f2bf(a0[1]);
        t[2] = (short)f2bf(a0[2]); t[3] = (short)f2bf(a0[3]);
        t[4] = (short)f2bf(a1[0]); t[5] = (short)f2bf(a1[1]);
        t[6] = (short)f2bf(a1[2]); t[7] = (short)f2bf(a1[3]);
        af[mr] = t;
      }
      #pragma unroll
      for (int nf = 0; nf < 8; ++nf){
        const short8 bf = *(const short8*)(wt + (nf * 16 + l16) * 128 + ks * 32 + lg * 8);
        acc[0][nf] = __builtin_amdgcn_mfma_f32_16x16x32_bf16(af[0], bf, acc[0][nf], 0, 0, 0);
        acc[1][nf] = __builtin_amdgcn_mfma_f32_16x16x32_bf16(af[1], bf, acc[1][nf], 0, 0, 0);
      }
    }

    if (g == 2){
      // direct transposed store: Vt[(t*B+b)*128 + ch][yx]
      const int tb = (m0) / YX_;                 // constant within tile
      const int yx0 = m0 % YX_;
      #pragma unroll
      for (int mr = 0; mr < 2; ++mr)
        #pragma unroll
        for (int nf = 0; nf < 8; ++nf){
          const int ch = nf * 16 + l16;
          const int yx = yx0 + w * 32 + mr * 16 + lg * 4;
          uint2 pk;
          pk.x = (u32)f2bf(acc[mr][nf][0]) | ((u32)f2bf(acc[mr][nf][1]) << 16);
          pk.y = (u32)f2bf(acc[mr][nf][2]) | ((u32)f2bf(acc[mr][nf][3]) << 16);
          *(uint2*)(Vt + ((size_t)tb * 128 + ch) * YX_ + yx) = pk;
        }
    } else {
      #pragma unroll
      for (int mr = 0; mr < 2; ++mr)
        #pragma unroll
        for (int nf = 0; nf < 8; ++nf)
          #pragma unroll
          for (int i = 0; i < 4; ++i)
            tile[(w * 32 + mr * 16 + lg * 4 + i) * 128 + nf * 16 + l16] = acc[mr][nf][i];
      __syncthreads();

      u16* outp = (g == 0) ? Qb : Kb;
      #pragma unroll
      for (int it = 0; it < 16; ++it){
        const int idx = it * 256 + tid;
        const int r = idx >> 5;
        const int c4 = (idx & 31) * 4;
        f32x4 v = *(const f32x4*)&tile[r * 128 + c4];
        const int p = m0 + r;
        const int t = p / (B_ * YX_);
        const float* te = temp_emb + t * 128 + c4;
        v[0] += te[0]; v[1] += te[1]; v[2] += te[2]; v[3] += te[3];
        if (g == 0){                          // query spatial emb + prescale
          const int yx = p % YX_;
          const int y = yx / X_, x = yx % X_;
          const int yrel = y - clampi(y, 2, Y_ - 3) + 2;
          const int xrel = x - clampi(x, 2, X_ - 3) + 2;
          const float* se = spatial_emb + (yrel * 5 + xrel) * 128 + c4;
          v[0] = (v[0] + se[0]) * 0.25f; v[1] = (v[1] + se[1]) * 0.25f;
          v[2] = (v[2] + se[2]) * 0.25f; v[3] = (v[3] + se[3]) * 0.25f;
        }
        uint2 pk;
        pk.x = (u32)f2bf(v[0]) | ((u32)f2bf(v[1]) << 16);
        pk.y = (u32)f2bf(v[2]) | ((u32)f2bf(v[3]) << 16);
        *(uint2*)(outp + (size_t)p * 128 + c4) = pk;
      }
      __syncthreads();
    }
  }
}

// ---------------- kernel 2: MFMA local spatio-temporal attention ----------------
// wave = (4x4 site tile, q-frame). Keys = 8x8 patch x 3 frames. 2 waves/block.
__global__ __launch_bounds__(128) void attn_kernel(
    const u16* __restrict__ Kb, const u16* __restrict__ Vt,
    u16* __restrict__ Qb, const u16* __restrict__ se_bf){
  __shared__ u16 qse_lds[2][3200];   // [site16][soff25][head8] bf16
  __shared__ u16 p_lds[2][4096];     // [head8][site16][key32] bf16, XOR-swizzled; reused as out-bounce
  const int tid = threadIdx.x;
  const int w = tid >> 6, l = tid & 63;
  const int lg = l >> 4, l16 = l & 15;
  const int j2 = l16 >> 1, par = l16 & 1;
  const int wid = blockIdx.x * 2 + w;
  const int q = wid / NTILE_;
  const int tau = wid % NTILE_;
  const int x0 = (tau % 48) * 4;
  const int y0 = ((tau / 48) % 48) * 4;
  const int b = tau / 2304;
  const int xbase = clampi(x0 - 2, 0, 184);
  const int ybase = clampi(y0 - 2, 0, 184);
  const int ycl = clampi(y0 + lg, 2, 189);
  const bool bval = (par == (lg >> 1));        // B-frag validity (block-diag head packing)
  const short8 z8 = {0,0,0,0,0,0,0,0};
  const f32x4 zf = {0.f,0.f,0.f,0.f};

  // ---- Q A-fragments (A row m=l16 -> site (y0+(m>>2), x0+(m&3))) ----
  const int ay = y0 + (l16 >> 2), ax = x0 + (l16 & 3);
  const size_t qrow = ((size_t)((q * B_ + b) * Y_ + ay) * X_ + ax) * 128;
  short8 qf[4];
  #pragma unroll
  for (int hp = 0; hp < 4; ++hp)
    qf[hp] = *(const short8*)(Qb + qrow + hp * 32 + lg * 8);

  // ---- qse[site][soff][head] = Qs . se  via MFMA ----
  u16* qsl = qse_lds[w];
  #pragma unroll
  for (int og = 0; og < 4; ++og){
    const int soff = og * 8 + j2;
    const int soffc = soff > 24 ? 24 : soff;
    #pragma unroll
    for (int hp = 0; hp < 4; ++hp){
      short8 ef = z8;
      if (bval) ef = *(const short8*)(se_bf + soffc * 128 + hp * 32 + lg * 8);
      f32x4 d = __builtin_amdgcn_mfma_f32_16x16x32_bf16(qf[hp], ef, zf, 0, 0, 0);
      if (soff <= 24){
        const int h = 2 * hp + par;
        #pragma unroll
        for (int i = 0; i < 4; ++i)
          qsl[((lg * 4 + i) * 25 + soff) * 8 + h] = f2bf(d[i]);
      }
    }
  }

  // per-i x constants (D rows: site y=y0+lg, x=x0+i)
  int dxc[4]; bool vx[4];
  #pragma unroll
  for (int i = 0; i < 4; ++i){
    const int xci = clampi(x0 + i, 2, 189);
    const int dx = xbase + j2 - xci + 2;
    vx[i] = ((unsigned)dx <= 4u);
    dxc[i] = clampi(dx, 0, 4);
  }

  f32x4 acc[8];
  #pragma unroll
  for (int h = 0; h < 8; ++h) acc[h] = zf;
  float lp[4][4];
  #pragma unroll
  for (int hp = 0; hp < 4; ++hp)
    #pragma unroll
    for (int i = 0; i < 4; ++i) lp[hp][i] = 0.f;
  u16* pl = p_lds[w];

  for (int t = 0; t < 3; ++t){
    const u16* kbt = Kb + (size_t)((t * B_ + b) * YX_) * 128;
    const u16* vbt = Vt + (size_t)((t * B_ + b) * 128) * YX_;
    #pragma unroll
    for (int ks2 = 0; ks2 < 2; ++ks2){
      #pragma unroll
      for (int kg4 = 0; kg4 < 4; ++kg4){
        const int kg = ks2 * 4 + kg4;
        const int ky = ybase + kg;
        const int dy = ky - ycl + 2;
        const bool rv = ((unsigned)dy <= 4u);
        const int dyc = clampi(dy, 0, 4);
        const u16* kp = kbt + (size_t)(ky * X_ + xbase + j2) * 128;
        f32x4 sc[4];
        #pragma unroll
        for (int hp = 0; hp < 4; ++hp){
          short8 kf = z8;
          if (bval) kf = *(const short8*)(kp + hp * 32 + lg * 8);
          sc[hp] = __builtin_amdgcn_mfma_f32_16x16x32_bf16(qf[hp], kf, zf, 0, 0, 0);
        }
        u32x4 qv[4];
        #pragma unroll
        for (int i = 0; i < 4; ++i)
          qv[i] = *(const u32x4*)&qsl[((lg * 4 + i) * 25 + dyc * 5 + dxc[i]) * 8];
        #pragma unroll
        for (int hp = 0; hp < 4; ++hp){
          #pragma unroll
          for (int i = 0; i < 4; ++i){
            const u32 wrd = qv[i][hp];
            const float qe = par ? bfhi(wrd) : bflo(wrd);
            const float s = sc[hp][i] + qe;
            const float p = (rv && vx[i]) ? __expf(s) : 0.f;
            lp[hp][i] += p;
            const int row = (2 * hp + par) * 16 + lg * 4 + i;
            const int byteoff = (row * 64 + (kg4 * 8 + j2) * 2) ^ ((row & 7) << 4);
            pl[byteoff >> 1] = f2bf_fast(p);
          }
        }
      }
      // ---- PV for this 32-key step ----
      #pragma unroll
      for (int h = 0; h < 8; ++h){
        const int row = h * 16 + l16;
        const int byteoff = (row * 64 + lg * 16) ^ ((row & 7) << 4);
        const short8 pa = *(const short8*)&pl[byteoff >> 1];
        const u16* vp = vbt + (size_t)(h * 16 + l16) * YX_ + (size_t)(ybase + ks2 * 4 + lg) * X_ + xbase;
        u32x4 vv;                                   // 4B-aligned loads (xbase even only)
        vv[0] = *(const u32*)(vp + 0); vv[1] = *(const u32*)(vp + 2);
        vv[2] = *(const u32*)(vp + 4); vv[3] = *(const u32*)(vp + 6);
        const short8 vb = __builtin_bit_cast(short8, vv);
        acc[h] = __builtin_amdgcn_mfma_f32_16x16x32_bf16(pa, vb, acc[h], 0, 0, 0);
      }
    }
  }

  // ---- finalize: l-reduce over the 8 kx-lanes, divide, store via LDS bounce ----
  float lv[4][4];
  #pragma unroll
  for (int hp = 0; hp < 4; ++hp)
    #pragma unroll
    for (int i = 0; i < 4; ++i){
      float s = lp[hp][i];
      s += __shfl_xor(s, 2); s += __shfl_xor(s, 4); s += __shfl_xor(s, 8);
      lv[hp][i] = s;
    }
  #pragma unroll
  for (int h = 0; h < 8; ++h){
    #pragma unroll
    for (int i = 0; i < 4; ++i){
      const float own = lv[h >> 1][i];
      const float oth = __shfl_xor(own, 1);
      const float lh = (par == (h & 1)) ? own : oth;
      const float o = acc[h][i] / lh;
      pl[(lg * 4 + i) * 128 + h * 16 + l16] = f2bf(o);
    }
  }
  // read back rows, store bf16 out over Qb
  {
    const int m = l >> 2, seg = l & 3;
    const int oy = y0 + (m >> 2), ox = x0 + (m & 3);
    u16* dst = Qb + ((size_t)((q * B_ + b) * Y_ + oy) * X_ + ox) * 128 + seg * 32;
    #pragma unroll
    for (int k = 0; k < 4; ++k){
      const u32x4 vv = *(const u32x4*)&pl[m * 128 + seg * 32 + k * 8];
      *(u32x4*)(dst + k * 8) = vv;
    }
  }
}

// ---------------- kernel 3: output projection (attnout x Wout) ----------------
__global__ __launch_bounds__(256) void out_kernel(
    const u16* __restrict__ Ab, const u16* __restrict__ WT3, float* __restrict__ out){
  const int tid = threadIdx.x;
  const int w = tid >> 6, l = tid & 63;
  const int l16 = l & 15, lg = l >> 4;
  const int m0 = blockIdx.x * 128;

  f32x4 acc[2][8];
  #pragma unroll
  for (int mr = 0; mr < 2; ++mr)
    #pragma unroll
    for (int nf = 0; nf < 8; ++nf)
      acc[mr][nf] = (f32x4){0.f, 0.f, 0.f, 0.f};

  #pragma unroll
  for (int ks = 0; ks < 4; ++ks){
    short8 af[2];
    #pragma unroll
    for (int mr = 0; mr < 2; ++mr)
      af[mr] = *(const short8*)(Ab + (size_t)(m0 + w * 32 + mr * 16 + l16) * 128 + ks * 32 + lg * 8);
    #pragma unroll
    for (int nf = 0; nf < 8; ++nf){
      const short8 bf = *(const short8*)(WT3 + (nf * 16 + l16) * 128 + ks * 32 + lg * 8);
      acc[0][nf] = __builtin_amdgcn_mfma_f32_16x16x32_bf16(af[0], bf, acc[0][nf], 0, 0, 0);
      acc[1][nf] = __builtin_amdgcn_mfma_f32_16x16x32_bf16(af[1], bf, acc[1][nf], 0, 0, 0);
    }
  }

  #pragma unroll
  for (int mr = 0; mr < 2; ++mr)
    #pragma unroll
    for (int nf = 0; nf < 8; ++nf)
      #pragma unroll
      for (int i = 0; i < 4; ++i)
        out[(size_t)(m0 + w * 32 + mr * 16 + lg * 4 + i) * 128 + nf * 16 + l16] = acc[mr][nf][i];
}

extern "C" void kernel_launch(void* const* d_in, const int* in_sizes, int n_in,
                              void* d_out, int out_size, void* d_ws, size_t ws_size,
                              hipStream_t stream){
  const float* frames      = (const float*)d_in[0];
  const float* Wq          = (const float*)d_in[1];
  const float* Wk          = (const float*)d_in[2];
  const float* Wv          = (const float*)d_in[3];
  const float* Wo          = (const float*)d_in[4];
  const float* temp_emb    = (const float*)d_in[5];
  const float* spatial_emb = (const float*)d_in[6];

  u16* WT    = (u16*)d_ws;                      // [4][128][128] bf16
  u16* se_bf = WT + 4 * 16384;                  // [25][128] bf16
  u16* Qb    = WT + 68736;                      // [N_][128] bf16 (Q, then attnout)
  u16* Kb    = (u16*)d_out;                     // [N_][128] bf16
  u16* Vt    = Kb + (size_t)N_ * 128;           // [6][128][YX_] bf16 transposed
  float* out = (float*)d_out;

  wt_kernel<<<269, 256, 0, stream>>>(Wq, Wk, Wv, Wo, spatial_emb, WT, se_bf);
  qkv_kernel<<<N_ / 128, 256, 0, stream>>>(frames, WT, Qb, Kb, Vt, temp_emb, spatial_emb);
  attn_kernel<<<NTILE_ * 3 / 2, 128, 0, stream>>>(Kb, Vt, Qb, se_bf);
  out_kernel<<<N_ / 128, 256, 0, stream>>>(Qb, WT + 3 * 16384, out);
}

// Round 3
// 773.750 us; speedup vs baseline: 1.3529x; 1.3529x over previous
//
#include <hip/hip_runtime.h>
#include <cstdint>
#include <cstddef>

#define T_ 3
#define B_ 2
#define Y_ 192
#define X_ 192
#define YX_ 36864          // Y_*X_
#define N_ 221184          // T_*B_*Y_*X_
#define NS_ 73728          // B_*Y_*X_

typedef __attribute__((ext_vector_type(8))) short short8;
typedef __attribute__((ext_vector_type(4))) float f32x4;
typedef __attribute__((ext_vector_type(2))) float f32x2;
typedef unsigned short u16;
typedef unsigned int u32;

__device__ __forceinline__ u16 f2bf(float f){
  u32 x = __builtin_bit_cast(u32, f);
  x += 0x7fffu + ((x >> 16) & 1u);          // RNE
  return (u16)(x >> 16);
}
__device__ __forceinline__ float bflo(u32 u){ return __builtin_bit_cast(float, u << 16); }
__device__ __forceinline__ float bfhi(u32 u){ return __builtin_bit_cast(float, u & 0xffff0000u); }
__device__ __forceinline__ f32x2 bfp(u32 u){
  f32x2 r; r.x = bflo(u); r.y = bfhi(u); return r;
}
__device__ __forceinline__ int clampi(int v, int lo, int hi){ return v < lo ? lo : (v > hi ? hi : v); }
__device__ __forceinline__ f32x2 shfl2(f32x2 v, int m){
  f32x2 r; r.x = __shfl_xor(v.x, m); r.y = __shfl_xor(v.y, m); return r;
}

// ---------------- kernel 0: transpose weights to bf16, n-major ----------------
__global__ __launch_bounds__(256) void wt_kernel(
    const float* __restrict__ Wq, const float* __restrict__ Wk,
    const float* __restrict__ Wv, const float* __restrict__ Wo,
    u16* __restrict__ WT){
  int idx = blockIdx.x * 256 + threadIdx.x;     // 65536 total
  int g = idx >> 14;
  int r = (idx >> 7) & 127;                     // k
  int c = idx & 127;                            // n
  const float* W = (g == 0) ? Wq : (g == 1) ? Wk : (g == 2) ? Wv : Wo;
  WT[g * 16384 + c * 128 + r] = f2bf(W[r * 128 + c]);
}

// ---------------- kernel 1: fused QKV projection + embeddings ----------------
// grid (N_/128, 3); g 0=Q ((v+se+te)*0.25), 1=K (+te), 2=V
__global__ __launch_bounds__(256) void qkv_kernel(
    const float* __restrict__ frames, const u16* __restrict__ WT,
    u16* __restrict__ Qb, u16* __restrict__ Kb, u16* __restrict__ Vb,
    const float* __restrict__ temp_emb, const float* __restrict__ spatial_emb){
  __shared__ float tile[128 * 128];
  const int tid = threadIdx.x;
  const int w = tid >> 6, l = tid & 63;
  const int l16 = l & 15, lg = l >> 4;
  const int g = blockIdx.y;
  const int m0 = blockIdx.x * 128;
  const u16* wt = WT + g * 16384;

  f32x4 acc[2][8];
  #pragma unroll
  for (int mr = 0; mr < 2; ++mr)
    #pragma unroll
    for (int nf = 0; nf < 8; ++nf)
      acc[mr][nf] = (f32x4){0.f, 0.f, 0.f, 0.f};

  #pragma unroll
  for (int ks = 0; ks < 4; ++ks){
    short8 af[2];
    #pragma unroll
    for (int mr = 0; mr < 2; ++mr){
      const float* ap = frames + (size_t)(m0 + w * 32 + mr * 16 + l16) * 128 + ks * 32 + lg * 8;
      const f32x4 a0 = *(const f32x4*)ap;
      const f32x4 a1 = *(const f32x4*)(ap + 4);
      short8 t;
      t[0] = (short)f2bf(a0[0]); t[1] = (short)f2bf(a0[1]);
      t[2] = (short)f2bf(a0[2]); t[3] = (short)f2bf(a0[3]);
      t[4] = (short)f2bf(a1[0]); t[5] = (short)f2bf(a1[1]);
      t[6] = (short)f2bf(a1[2]); t[7] = (short)f2bf(a1[3]);
      af[mr] = t;
    }
    #pragma unroll
    for (int nf = 0; nf < 8; ++nf){
      const short8 bf = *(const short8*)(wt + (nf * 16 + l16) * 128 + ks * 32 + lg * 8);
      acc[0][nf] = __builtin_amdgcn_mfma_f32_16x16x32_bf16(af[0], bf, acc[0][nf], 0, 0, 0);
      acc[1][nf] = __builtin_amdgcn_mfma_f32_16x16x32_bf16(af[1], bf, acc[1][nf], 0, 0, 0);
    }
  }

  #pragma unroll
  for (int mr = 0; mr < 2; ++mr)
    #pragma unroll
    for (int nf = 0; nf < 8; ++nf)
      #pragma unroll
      for (int i = 0; i < 4; ++i)
        tile[(w * 32 + mr * 16 + lg * 4 + i) * 128 + nf * 16 + l16] = acc[mr][nf][i];
  __syncthreads();

  u16* outp = (g == 0) ? Qb : (g == 1) ? Kb : Vb;
  #pragma unroll
  for (int it = 0; it < 16; ++it){
    const int idx = it * 256 + tid;
    const int r = idx >> 5;
    const int c4 = (idx & 31) * 4;
    f32x4 v = *(const f32x4*)&tile[r * 128 + c4];
    const int p = m0 + r;
    const int t = p / (B_ * YX_);
    if (g <= 1){                          // temporal emb for Q and K
      const float* te = temp_emb + t * 128 + c4;
      v[0] += te[0]; v[1] += te[1]; v[2] += te[2]; v[3] += te[3];
    }
    if (g == 0){                          // query spatial emb + 1/sqrt(F) prescale
      const int yx = p % YX_;
      const int y = yx / X_, x = yx % X_;
      const int yrel = y - clampi(y, 2, Y_ - 3) + 2;
      const int xrel = x - clampi(x, 2, X_ - 3) + 2;
      const float* se = spatial_emb + (yrel * 5 + xrel) * 128 + c4;
      v[0] = (v[0] + se[0]) * 0.25f; v[1] = (v[1] + se[1]) * 0.25f;
      v[2] = (v[2] + se[2]) * 0.25f; v[3] = (v[3] + se[3]) * 0.25f;
    }
    uint2 pk;
    pk.x = (u32)f2bf(v[0]) | ((u32)f2bf(v[1]) << 16);
    pk.y = (u32)f2bf(v[2]) | ((u32)f2bf(v[3]) << 16);
    *(uint2*)(outp + (size_t)p * 128 + c4) = pk;
  }
}

// ---------------- kernel 2: scalar attention, 8 key-slots x 8 heads per wave ----------------
// 1 wave per site; lane (slot=l>>3, h=l&7) owns all 16 ch of head h for keys slot, slot+8, ...
__global__ __launch_bounds__(256) void attn_kernel(
    const u16* __restrict__ Kb, const u16* __restrict__ Vb,
    u16* __restrict__ Qb, const float* __restrict__ se){
  __shared__ float qse[4][3][25][8];
  const int tid = threadIdx.x;
  const int w = tid >> 6, l = tid & 63;
  const int slot = l >> 3, h = l & 7;
  const int site = blockIdx.x * 4 + w;
  const int b = site / YX_;
  const int yx = site % YX_;
  const int y = yx / X_, x = yx % X_;
  const int yc = clampi(y, 2, Y_ - 3), xc = clampi(x, 2, X_ - 3);

  // Q load + unpack to float2 (already prescaled, + temp & query-spatial emb)
  f32x2 qpf[3][8];
  #pragma unroll
  for (int q = 0; q < 3; ++q){
    const u16* qp = Qb + ((size_t)((q * B_ + b) * Y_ + y) * X_ + x) * 128 + h * 16;
    const uint4 a = *(const uint4*)qp;
    const uint4 c = *(const uint4*)(qp + 8);
    qpf[q][0] = bfp(a.x); qpf[q][1] = bfp(a.y); qpf[q][2] = bfp(a.z); qpf[q][3] = bfp(a.w);
    qpf[q][4] = bfp(c.x); qpf[q][5] = bfp(c.y); qpf[q][6] = bfp(c.z); qpf[q][7] = bfp(c.w);
  }

  // qse[q][s][h] = Qs . spatial_emb[s] (per head), s striped over slots
  #pragma unroll
  for (int sj = 0; sj < 4; ++sj){
    const int so = sj * 8 + slot;
    if (so < 25){
      const float* sp = se + so * 128 + h * 16;
      const f32x4 s0 = *(const f32x4*)sp;
      const f32x4 s1 = *(const f32x4*)(sp + 4);
      const f32x4 s2 = *(const f32x4*)(sp + 8);
      const f32x4 s3 = *(const f32x4*)(sp + 12);
      f32x2 sf[8];
      sf[0] = (f32x2){s0[0], s0[1]}; sf[1] = (f32x2){s0[2], s0[3]};
      sf[2] = (f32x2){s1[0], s1[1]}; sf[3] = (f32x2){s1[2], s1[3]};
      sf[4] = (f32x2){s2[0], s2[1]}; sf[5] = (f32x2){s2[2], s2[3]};
      sf[6] = (f32x2){s3[0], s3[1]}; sf[7] = (f32x2){s3[2], s3[3]};
      #pragma unroll
      for (int q = 0; q < 3; ++q){
        f32x2 dv = qpf[q][0] * sf[0];
        #pragma unroll
        for (int i = 1; i < 8; ++i) dv += qpf[q][i] * sf[i];
        qse[w][q][so][h] = dv.x + dv.y;
      }
    }
  }
  __syncthreads();

  float ll[3] = {0.f, 0.f, 0.f};
  f32x2 acc[3][8];
  #pragma unroll
  for (int q = 0; q < 3; ++q)
    #pragma unroll
    for (int i = 0; i < 8; ++i) acc[q][i] = (f32x2){0.f, 0.f};

  #pragma unroll 2
  for (int j = 0; j < 10; ++j){
    const int kk = j * 8 + slot;
    const bool valid = (kk < 75);
    const int kkc = valid ? kk : 74;
    const int t = (kkc >= 50) ? 2 : ((kkc >= 25) ? 1 : 0);
    const int s = kkc - t * 25;
    const int dy = s / 5, dx = s - dy * 5;
    const int ky = yc + dy - 2, kx = xc + dx - 2;
    const size_t roff = ((size_t)(((t * B_ + b) * Y_ + ky) * X_ + kx)) * 128 + h * 16;
    const uint4 k0 = *(const uint4*)(Kb + roff);
    const uint4 k1 = *(const uint4*)(Kb + roff + 8);
    const uint4 v0 = *(const uint4*)(Vb + roff);
    const uint4 v1 = *(const uint4*)(Vb + roff + 8);
    f32x2 kf[8], vf[8];
    kf[0] = bfp(k0.x); kf[1] = bfp(k0.y); kf[2] = bfp(k0.z); kf[3] = bfp(k0.w);
    kf[4] = bfp(k1.x); kf[5] = bfp(k1.y); kf[6] = bfp(k1.z); kf[7] = bfp(k1.w);
    vf[0] = bfp(v0.x); vf[1] = bfp(v0.y); vf[2] = bfp(v0.z); vf[3] = bfp(v0.w);
    vf[4] = bfp(v1.x); vf[5] = bfp(v1.y); vf[6] = bfp(v1.z); vf[7] = bfp(v1.w);

    #pragma unroll
    for (int q = 0; q < 3; ++q){
      f32x2 dv = qpf[q][0] * kf[0];
      #pragma unroll
      for (int i = 1; i < 8; ++i) dv += qpf[q][i] * kf[i];
      const float d = dv.x + dv.y + qse[w][q][s][h];
      const float p = valid ? __expf(d) : 0.f;
      ll[q] += p;
      const f32x2 pp = {p, p};
      #pragma unroll
      for (int i = 0; i < 8; ++i) acc[q][i] += pp * vf[i];
    }
  }

  // merge across the 8 key-slot groups (lanes xor 8/16/32 share the same head)
  #pragma unroll
  for (int q = 0; q < 3; ++q){
    ll[q] += __shfl_xor(ll[q], 8);
    ll[q] += __shfl_xor(ll[q], 16);
    ll[q] += __shfl_xor(ll[q], 32);
    #pragma unroll
    for (int i = 0; i < 8; ++i){
      acc[q][i] += shfl2(acc[q][i], 8);
      acc[q][i] += shfl2(acc[q][i], 16);
      acc[q][i] += shfl2(acc[q][i], 32);
    }
  }

  // slot q (<3) stores query-frame q's output over its Q row
  if (slot < 3){
    const int q = slot;
    const float inv = __builtin_amdgcn_rcpf(ll[q]);
    u32 o[8];
    #pragma unroll
    for (int i = 0; i < 8; ++i){
      const f32x2 t2 = acc[q][i] * inv;
      o[i] = (u32)f2bf(t2.x) | ((u32)f2bf(t2.y) << 16);
    }
    u16* dst = Qb + ((size_t)((q * B_ + b) * Y_ + y) * X_ + x) * 128 + h * 16;
    uint4 pk0; pk0.x = o[0]; pk0.y = o[1]; pk0.z = o[2]; pk0.w = o[3];
    uint4 pk1; pk1.x = o[4]; pk1.y = o[5]; pk1.z = o[6]; pk1.w = o[7];
    *(uint4*)dst = pk0;
    *(uint4*)(dst + 8) = pk1;
  }
}

// ---------------- kernel 3: output projection (attnout x Wout) ----------------
__global__ __launch_bounds__(256) void out_kernel(
    const u16* __restrict__ Ab, const u16* __restrict__ WT3, float* __restrict__ out){
  const int tid = threadIdx.x;
  const int w = tid >> 6, l = tid & 63;
  const int l16 = l & 15, lg = l >> 4;
  const int m0 = blockIdx.x * 128;

  f32x4 acc[2][8];
  #pragma unroll
  for (int mr = 0; mr < 2; ++mr)
    #pragma unroll
    for (int nf = 0; nf < 8; ++nf)
      acc[mr][nf] = (f32x4){0.f, 0.f, 0.f, 0.f};

  #pragma unroll
  for (int ks = 0; ks < 4; ++ks){
    short8 af[2];
    #pragma unroll
    for (int mr = 0; mr < 2; ++mr)
      af[mr] = *(const short8*)(Ab + (size_t)(m0 + w * 32 + mr * 16 + l16) * 128 + ks * 32 + lg * 8);
    #pragma unroll
    for (int nf = 0; nf < 8; ++nf){
      const short8 bf = *(const short8*)(WT3 + (nf * 16 + l16) * 128 + ks * 32 + lg * 8);
      acc[0][nf] = __builtin_amdgcn_mfma_f32_16x16x32_bf16(af[0], bf, acc[0][nf], 0, 0, 0);
      acc[1][nf] = __builtin_amdgcn_mfma_f32_16x16x32_bf16(af[1], bf, acc[1][nf], 0, 0, 0);
    }
  }

  #pragma unroll
  for (int mr = 0; mr < 2; ++mr)
    #pragma unroll
    for (int nf = 0; nf < 8; ++nf)
      #pragma unroll
      for (int i = 0; i < 4; ++i)
        out[(size_t)(m0 + w * 32 + mr * 16 + lg * 4 + i) * 128 + nf * 16 + l16] = acc[mr][nf][i];
}

extern "C" void kernel_launch(void* const* d_in, const int* in_sizes, int n_in,
                              void* d_out, int out_size, void* d_ws, size_t ws_size,
                              hipStream_t stream){
  const float* frames      = (const float*)d_in[0];
  const float* Wq          = (const float*)d_in[1];
  const float* Wk          = (const float*)d_in[2];
  const float* Wv          = (const float*)d_in[3];
  const float* Wo          = (const float*)d_in[4];
  const float* temp_emb    = (const float*)d_in[5];
  const float* spatial_emb = (const float*)d_in[6];

  u16* WT = (u16*)d_ws;                        // [4][128][128] bf16 (n-major)
  u16* Qb = WT + 4 * 16384;                    // [N_][128] bf16 (Q, then attnout)
  u16* Kb = (u16*)d_out;                       // [N_][128] bf16 — reuse output buffer
  u16* Vb = Kb + (size_t)N_ * 128;             // [N_][128] bf16 — exactly fills d_out
  float* out = (float*)d_out;

  wt_kernel<<<256, 256, 0, stream>>>(Wq, Wk, Wv, Wo, WT);
  qkv_kernel<<<dim3(N_ / 128, 3), 256, 0, stream>>>(frames, WT, Qb, Kb, Vb, temp_emb, spatial_emb);
  attn_kernel<<<NS_ / 4, 256, 0, stream>>>(Kb, Vb, Qb, spatial_emb);
  out_kernel<<<N_ / 128, 256, 0, stream>>>(Qb, WT + 3 * 16384, out);
}